// Round 1
// baseline (257.995 us; speedup 1.0000x reference)
//
#include <hip/hip_runtime.h>
#include <stdint.h>
#include <math.h>

// Match XLA's default (non-contracted) f32 arithmetic: keeps floor()/compare
// boundaries (bilinear taps, erase box, gridmask) aligned with the reference.
#pragma clang fp contract(off)

struct KeyPair { uint32_t hi, lo; };
struct KTab { KeyPair k[17]; };   // per-param derived keys, see host code

__host__ __device__ __forceinline__ uint32_t rotl32(uint32_t x, int r) {
  return (x << r) | (x >> (32 - r));
}

// JAX threefry2x32: 20 rounds, key injection every 4.
__host__ __device__ __forceinline__ void threefry2x32(uint32_t k0, uint32_t k1,
                                                      uint32_t x0, uint32_t x1,
                                                      uint32_t& o0, uint32_t& o1) {
  const uint32_t ks0 = k0, ks1 = k1, ks2 = k0 ^ k1 ^ 0x1BD11BDAu;
  x0 += ks0; x1 += ks1;
#define TF_R(r) { x0 += x1; x1 = rotl32(x1, (r)); x1 ^= x0; }
  TF_R(13) TF_R(15) TF_R(26) TF_R(6)
  x0 += ks1; x1 += ks2 + 1u;
  TF_R(17) TF_R(29) TF_R(16) TF_R(24)
  x0 += ks2; x1 += ks0 + 2u;
  TF_R(13) TF_R(15) TF_R(26) TF_R(6)
  x0 += ks0; x1 += ks1 + 3u;
  TF_R(17) TF_R(29) TF_R(16) TF_R(24)
  x0 += ks1; x1 += ks2 + 4u;
  TF_R(13) TF_R(15) TF_R(26) TF_R(6)
  x0 += ks2; x1 += ks0 + 5u;
#undef TF_R
  o0 = x0; o1 = x1;
}

// jax_threefry_partitionable=True 32-bit draw: fold both output words.
__host__ __device__ __forceinline__ uint32_t jax_rbits32(KeyPair k, uint32_t i) {
  uint32_t a, b; threefry2x32(k.hi, k.lo, 0u, i, a, b);
  return a ^ b;
}

__host__ __device__ __forceinline__ KeyPair jax_split_child(KeyPair k, uint32_t j) {
  uint32_t a, b; threefry2x32(k.hi, k.lo, 0u, j, a, b);
  KeyPair r; r.hi = a; r.lo = b; return r;
}

__host__ __device__ __forceinline__ float bits_to_unit(uint32_t bits) {
  uint32_t fb = (bits >> 9) | 0x3F800000u;
  return __builtin_bit_cast(float, fb) - 1.0f;   // u in [0,1)
}

__device__ __forceinline__ float map_u(float u, float mn, float mx) {
  return fmaxf(mn, u * (mx - mn) + mn);   // matches jax.random.uniform
}

struct SP {
  float m00, m01, m10, m11, txp, typ;
  float bb, cc, ssat;
  int flip, doblur, apply_e, apply_g;
};

// Bordered plane layout: row stride RS=65, addr(y,x) = (y+1)*65 + (x+1),
// valid for y in [-1,65], x in [-1,65]. Col x=64 folds onto the next row's
// left pad (addr (y+2)*65+0), so one pad column per row suffices. Rows 0
// (y=-1), 65 (y=64), 66 (weight-0 overreads from y0=64) and all pad cells
// hold 0.0f -> tap validity masking of the reference becomes free.
#define RS  65
#define PLS 4360   // 67*65 + tail, 16B-aligned plane stride (floats)

__global__ __launch_bounds__(512, 6) void aug_kernel(const float* __restrict__ in,
                                                     float* __restrict__ out,
                                                     KTab KT, KeyPair kv, int B) {
  const int b = blockIdx.x;
  const int tid = threadIdx.x;
  __shared__ float simg[3 * PLS];   // 52320 B: 3 bordered planes
  __shared__ SP sp;
  __shared__ unsigned long long mgrid, merow, mecol;
  __shared__ float red[8];

  const float* __restrict__ inb = in + (size_t)b * 12288;

  // ---- issue all staging loads first (latency hides under the param phase) ----
  float4 st[6];
#pragma unroll
  for (int it = 0; it < 6; ++it) st[it] = ((const float4*)inb)[tid + it * 512];

  // ---- wave 0: draws + params + ballot masks, entirely barrier-free ----
  if (tid < 64) {
    float myu = 0.f;
    if (tid < 17) {
      KeyPair k = KT.k[tid];
      uint32_t i = (tid == 3) ? 2u * (uint32_t)b
                 : (tid == 4) ? 2u * (uint32_t)b + 1u
                 : (uint32_t)b;
      myu = bits_to_unit(jax_rbits32(k, i));
    }
    float u[17];
#pragma unroll
    for (int j = 0; j < 17; ++j) u[j] = __shfl(myu, j);

    const float DEG = 0.017453292519943295f;
    const float ang = map_u(u[0], -25.f, 25.f) * DEG;
    const float shr = map_u(u[1], -15.f, 15.f) * DEG;
    const float scl = map_u(u[2], 0.85f, 1.15f);
    const float t_x = map_u(u[3], -0.15f, 0.15f) * 64.f;
    const float t_y = map_u(u[4], -0.15f, 0.15f) * 64.f;
    const float cA = cosf(ang), sA = sinf(ang), tS = tanf(shr);
    float area = map_u(u[10], 0.02f, 0.1f);
    area = area * 64.f;   // mirror reference's (u * H) * W evaluation order
    area = area * 64.f;
    const float ratio = map_u(u[11], 0.3f, 3.0f);
    const float eh = fminf(fmaxf(sqrtf(area * ratio), 1.f), 64.f);
    const float ew = fminf(fmaxf(sqrtf(area / ratio), 1.f), 64.f);
    const float topv = u[12] * (64.f - eh);
    const float leftv = u[13] * (64.f - ew);
    const float dG = floorf(map_u(u[15], 8.f, 32.f));
    const float lG = floorf(dG * 0.6f);

    const float rf = (float)tid;   // H == W == 64: rows and cols share lanes
    const unsigned long long g  = __ballot(fmodf(rf, dG) < lG);
    const unsigned long long er = __ballot((rf >= topv) & (rf < (topv + eh)));
    const unsigned long long ec = __ballot((rf >= leftv) & (rf < (leftv + ew)));
    if (tid == 0) {
      sp.m00 = (cA - tS * (-sA)) / scl;
      sp.m01 = (sA - tS * cA) / scl;
      sp.m10 = (-sA) / scl;
      sp.m11 = cA / scl;
      sp.txp = t_x; sp.typ = t_y;
      sp.flip = u[5] < 0.6f;
      sp.bb = map_u(u[6], 0.7f, 1.3f);
      sp.cc = map_u(u[7], 0.7f, 1.3f);
      sp.ssat = map_u(u[8], 0.8f, 1.2f);
      sp.doblur = u[9] < 0.3f;
      sp.apply_e = u[14] < 0.3f;
      sp.apply_g = u[16] < 0.3f;
      mgrid = g; merow = er; mecol = ec;
    }
  } else if (tid < 328) {
    // ---- zero the 264 border cells per plane (disjoint from data cells) ----
    const int z = tid - 64;
    int a;
    if (z < 65)       a = z;              // row 0 (y=-1)
    else if (z < 200) a = 4160 + z;       // 4225..4359: rows 65,66 + tail
    else              a = (z - 199) * RS; // left pad col of rows 1..64
#pragma unroll
    for (int c = 0; c < 3; ++c) simg[c * PLS + a] = 0.f;
  }

  // ---- staged data -> bordered LDS (compiler inserts the vmcnt waits) ----
#pragma unroll
  for (int it = 0; it < 6; ++it) {
    const int f = it * 2048 + tid * 4;
    const int c = f >> 12;
    const int r = (f >> 6) & 63;
    const int cc = f & 63;
    float* d = &simg[c * PLS + (r + 1) * RS + cc + 1];
    d[0] = st[it].x; d[1] = st[it].y; d[2] = st[it].z; d[3] = st[it].w;
  }
  __syncthreads();   // staging + params + masks visible

  // snapshot params into registers
  const float m00 = sp.m00, m01 = sp.m01, m10 = sp.m10, m11 = sp.m11;
  const float txp = sp.txp, typ = sp.typ;
  const float bb = sp.bb, cc = sp.cc, ssat = sp.ssat;
  const int flip = sp.flip, doblur = sp.doblur;
  const int apply_e = sp.apply_e, apply_g = sp.apply_g;
  const unsigned long long mg = mgrid, mer = merow, mec = mecol;

  // ---- phase 1: affine warp + hflip, results held in registers ----
  // Mapping/weights computed once per pixel, shared by all 3 channels.
  // Taps are plain reads: border zeros reproduce the reference's validity
  // masking exactly (clamped sx,sy land on weight-0 / value-0 cells).
  float vv[3][8];
  float lsum = 0.f;
#pragma unroll
  for (int it = 0; it < 8; ++it) {
    const int p = tid + it * 512;
    const int h = p >> 6;
    const int w = p & 63;
    const int wsrc = flip ? (63 - w) : w;   // flip(warp(x))[w] == warp-out at 63-w
    const float gx = (float)wsrc - 31.5f;
    const float gy = (float)h - 31.5f;
    float sx = (m00 * gx + m01 * gy) - txp + 31.5f;
    float sy = (m10 * gx + m11 * gy) - typ + 31.5f;
    sx = fminf(fmaxf(sx, -1.f), 64.f);
    sy = fminf(fmaxf(sy, -1.f), 64.f);
    const float fx0 = floorf(sx), fy0 = floorf(sy);
    const float wx = sx - fx0, wy = sy - fy0;
    const float omx = 1.f - wx, omy = 1.f - wy;
    const float w00 = omx * omy, w01 = wx * omy, w10 = omx * wy, w11 = wx * wy;
    const int a = ((int)fy0 + 1) * RS + (int)fx0 + 1;
#pragma unroll
    for (int c = 0; c < 3; ++c) {
      const float* t = &simg[c * PLS + a];
      // adjacent pairs (t[0],t[1]) and (t[RS],t[RS+1]) merge into ds_read2_b32
      const float v = t[0] * w00 + t[1] * w01 + t[RS] * w10 + t[RS + 1] * w11;
      vv[c][it] = v;
      lsum += v;
    }
  }
  {
    float wsum = lsum;
    for (int off = 32; off > 0; off >>= 1) wsum += __shfl_down(wsum, off);
    if ((tid & 63) == 0) red[tid >> 6] = wsum;
  }
  __syncthreads();   // red[] visible; all tap reads of the planes complete

  // ---- color-jitter algebra (blur and pointwise-affine color commute):
  //   x3_c = A*x_c + G*grayx + m'     (A = s*cc*bb, G = (1-s)*cc*bb, m' = mean*(1-cc))
  //   blur(x3)_c = A*bx_c + G*(luma . bx) + m'*blur(1),  blur(1) = edge(h)*edge(w)
  const float mean = (bb * (red[0] + red[1] + red[2] + red[3] +
                            red[4] + red[5] + red[6] + red[7])) / 12288.f;
  const float Ac = ssat * cc * bb;
  const float Gc = (1.f - ssat) * cc * bb;
  const float mprime = mean * (1.f - cc);
  float* __restrict__ ob = out + (size_t)b * 12288;

  if (!doblur) {
    // ---- 70% path: straight from registers, zero further LDS traffic ----
#pragma unroll
    for (int it = 0; it < 8; ++it) {
      const int p = tid + it * 512;
      const int h = p >> 6, w = p & 63;
      const bool do_er = apply_e && ((mer >> h) & 1ull) && ((mec >> w) & 1ull);
      const bool do_gr = apply_g && ((mg >> h) & 1ull) && ((mg >> w) & 1ull);
      const float gray = 0.299f * vv[0][it] + 0.587f * vv[1][it] + 0.114f * vv[2][it];
#pragma unroll
      for (int c = 0; c < 3; ++c) {
        float v = Ac * vv[c][it] + Gc * gray + mprime;
        if (do_er) {
          const uint32_t idx = ((uint32_t)(b * 3 + c) << 12) | (uint32_t)p;
          v = bits_to_unit(jax_rbits32(kv, idx));   // uniform fill [0,1)
        }
        if (do_gr) v = 0.f;
        ob[c * 4096 + p] = fminf(fmaxf(v, 0.f), 1.f);   // lane-stride-1: coalesced
      }
    }
  } else {
    // ---- 30% path: write warped planes back (borders stay zero = blur pad) ----
#pragma unroll
    for (int it = 0; it < 8; ++it) {
      const int p = tid + it * 512;
      const int a = ((p >> 6) + 1) * RS + (p & 63) + 1;
#pragma unroll
      for (int c = 0; c < 3; ++c) simg[c * PLS + a] = vv[c][it];
    }
    __syncthreads();
#pragma unroll 1
    for (int it = 0; it < 2; ++it) {
      const int qq = tid + it * 512;        // quad id 0..1023
      const int h = qq >> 4;
      const int w0 = (qq & 15) * 4;
      float px[3][4];
#pragma unroll
      for (int c = 0; c < 3; ++c) {
        float win[3][6];
#pragma unroll
        for (int r = 0; r < 3; ++r) {
          // row (h-1+r), cols w0-1..w0+4; borders supply the zero padding.
          const float* row = &simg[c * PLS + (h + r) * RS + w0];
#pragma unroll
          for (int k = 0; k < 6; ++k) win[r][k] = row[k];
        }
#pragma unroll
        for (int j = 0; j < 4; ++j) {
          const float h0 = 0.25f * win[0][j] + 0.5f * win[0][j + 1] + 0.25f * win[0][j + 2];
          const float h1 = 0.25f * win[1][j] + 0.5f * win[1][j + 1] + 0.25f * win[1][j + 2];
          const float h2 = 0.25f * win[2][j] + 0.5f * win[2][j + 1] + 0.25f * win[2][j + 2];
          px[c][j] = 0.25f * h0 + 0.5f * h1 + 0.25f * h2;
        }
      }
      const float rowe = (h == 0 || h == 63) ? 0.75f : 1.f;
      const bool erow_b = apply_e && ((mer >> h) & 1ull);
      const bool grow_b = apply_g && ((mg >> h) & 1ull);
      float o[3][4];
#pragma unroll
      for (int j = 0; j < 4; ++j) {
        const int w = w0 + j;
        const float gray = 0.299f * px[0][j] + 0.587f * px[1][j] + 0.114f * px[2][j];
        const float cole = (w == 0 || w == 63) ? 0.75f : 1.f;
        const float moff = mprime * (rowe * cole);
        const bool do_er = erow_b && ((mec >> w) & 1ull);
        const bool do_gr = grow_b && ((mg >> w) & 1ull);
#pragma unroll
        for (int c = 0; c < 3; ++c) {
          float v = Ac * px[c][j] + Gc * gray + moff;
          if (do_er) {
            const uint32_t idx = ((uint32_t)(b * 3 + c) << 12) | (uint32_t)(h << 6) | (uint32_t)w;
            v = bits_to_unit(jax_rbits32(kv, idx));   // uniform fill [0,1)
          }
          if (do_gr) v = 0.f;
          o[c][j] = fminf(fmaxf(v, 0.f), 1.f);
        }
      }
#pragma unroll
      for (int c = 0; c < 3; ++c) {
        float4 stv; stv.x = o[c][0]; stv.y = o[c][1]; stv.z = o[c][2]; stv.w = o[c][3];
        *(float4*)&ob[c * 4096 + h * 64 + w0] = stv;
      }
    }
  }
}

extern "C" void kernel_launch(void* const* d_in, const int* in_sizes, int n_in,
                              void* d_out, int out_size, void* d_ws, size_t ws_size,
                              hipStream_t stream) {
  (void)n_in; (void)out_size; (void)d_ws; (void)ws_size;
  const float* x = (const float*)d_in[0];
  float* out = (float*)d_out;
  const int B = in_sizes[0] / (3 * 64 * 64);
  if (B <= 0) return;

  // Host-side key derivation (pure arithmetic; graph-capture safe).
  KeyPair root; root.hi = 0u; root.lo = 42u;           // jax.random.key(42)
  KeyPair kg = jax_split_child(root, 0);
  KeyPair kf = jax_split_child(root, 1);
  KeyPair kc = jax_split_child(root, 2);
  KeyPair kb = jax_split_child(root, 3);
  KeyPair ke = jax_split_child(root, 4);
  KeyPair km = jax_split_child(root, 5);

  KTab KT;
  KT.k[0]  = jax_split_child(kg, 0);   // angle
  KT.k[1]  = jax_split_child(kg, 1);   // shear
  KT.k[2]  = jax_split_child(kg, 2);   // scale
  KT.k[3]  = jax_split_child(kg, 3);   // translate x (idx 2b)
  KT.k[4]  = KT.k[3];                  // translate y (idx 2b+1)
  KT.k[5]  = kf;                       // hflip
  KT.k[6]  = jax_split_child(kc, 0);   // brightness
  KT.k[7]  = jax_split_child(kc, 1);   // contrast
  KT.k[8]  = jax_split_child(kc, 2);   // saturation
  KT.k[9]  = kb;                       // blur
  KT.k[10] = jax_split_child(ke, 0);   // area
  KT.k[11] = jax_split_child(ke, 1);   // ratio
  KT.k[12] = jax_split_child(ke, 2);   // top
  KT.k[13] = jax_split_child(ke, 3);   // left
  KT.k[14] = jax_split_child(ke, 5);   // apply (erase)
  KT.k[15] = jax_split_child(km, 0);   // grid d
  KT.k[16] = jax_split_child(km, 1);   // apply (grid)
  KeyPair kv = jax_split_child(ke, 4); // erase fill values

  aug_kernel<<<dim3(B), dim3(512), 0, stream>>>(x, out, KT, kv, B);
}

// Round 4
// 186.590 us; speedup vs baseline: 1.3827x; 1.3827x over previous
//
#include <hip/hip_runtime.h>
#include <stdint.h>
#include <math.h>

// Match XLA's default (non-contracted) f32 arithmetic: keeps floor()/compare
// boundaries (bilinear taps, erase box, gridmask) aligned with the reference.
#pragma clang fp contract(off)

struct KeyPair { uint32_t hi, lo; };
struct KTab { KeyPair k[17]; };   // per-param derived keys, see host code

__host__ __device__ __forceinline__ uint32_t rotl32(uint32_t x, int r) {
  return (x << r) | (x >> (32 - r));
}

// JAX threefry2x32: 20 rounds, key injection every 4.
__host__ __device__ __forceinline__ void threefry2x32(uint32_t k0, uint32_t k1,
                                                      uint32_t x0, uint32_t x1,
                                                      uint32_t& o0, uint32_t& o1) {
  const uint32_t ks0 = k0, ks1 = k1, ks2 = k0 ^ k1 ^ 0x1BD11BDAu;
  x0 += ks0; x1 += ks1;
#define TF_R(r) { x0 += x1; x1 = rotl32(x1, (r)); x1 ^= x0; }
  TF_R(13) TF_R(15) TF_R(26) TF_R(6)
  x0 += ks1; x1 += ks2 + 1u;
  TF_R(17) TF_R(29) TF_R(16) TF_R(24)
  x0 += ks2; x1 += ks0 + 2u;
  TF_R(13) TF_R(15) TF_R(26) TF_R(6)
  x0 += ks0; x1 += ks1 + 3u;
  TF_R(17) TF_R(29) TF_R(16) TF_R(24)
  x0 += ks1; x1 += ks2 + 4u;
  TF_R(13) TF_R(15) TF_R(26) TF_R(6)
  x0 += ks2; x1 += ks0 + 5u;
#undef TF_R
  o0 = x0; o1 = x1;
}

// jax_threefry_partitionable=True 32-bit draw: fold both output words.
__host__ __device__ __forceinline__ uint32_t jax_rbits32(KeyPair k, uint32_t i) {
  uint32_t a, b; threefry2x32(k.hi, k.lo, 0u, i, a, b);
  return a ^ b;
}

__host__ __device__ __forceinline__ KeyPair jax_split_child(KeyPair k, uint32_t j) {
  uint32_t a, b; threefry2x32(k.hi, k.lo, 0u, j, a, b);
  KeyPair r; r.hi = a; r.lo = b; return r;
}

__host__ __device__ __forceinline__ float bits_to_unit(uint32_t bits) {
  uint32_t fb = (bits >> 9) | 0x3F800000u;
  return __builtin_bit_cast(float, fb) - 1.0f;   // u in [0,1)
}

__device__ __forceinline__ float map_u(float u, float mn, float mx) {
  return fmaxf(mn, u * (mx - mn) + mn);   // matches jax.random.uniform
}

struct SP {
  float m00, m01, m10, m11, txp, typ;
  float bb, cc, ssat;
  int flip, doblur, apply_e, apply_g;
};

// Bordered plane layout: row stride RS=65, addr(y,x) = (y+1)*65 + (x+1),
// valid for y in [-1,65], x in [-1,65]. Col x=64 folds onto the next row's
// left pad (addr (y+2)*65+0), so one pad column per row suffices. Rows 0
// (y=-1), 65, 66 (weight-0 overreads from y0=64) and all pad cells
// hold 0.0f -> tap validity masking of the reference becomes free.
#define RS  65
#define PLS 4360   // 67*65 + tail, plane stride (floats)

// NOTE launch_bounds(512, 4): round-1 ran (512,6) -> VGPR capped at 40 ->
// st[6]+vv[3][8] spilled to scratch (WRITE_SIZE 98->316MB, 2x slowdown).
// min-waves 4/EU = 2 blocks/CU, VGPR cap 128: no spill, LDS 2x49.7KB fits.
__global__ __launch_bounds__(512, 4) void aug_kernel(const float* __restrict__ in,
                                                     float* __restrict__ out,
                                                     KTab KT, KeyPair kv, int B) {
  const int b = blockIdx.x;
  const int tid = threadIdx.x;
  __shared__ float simg[3 * PLS];   // 52320 B: 3 bordered planes
  __shared__ SP sp;
  __shared__ unsigned long long mgrid, merow, mecol;
  __shared__ float red[8];

  const float* __restrict__ inb = in + (size_t)b * 12288;

  // ---- issue all staging loads first (latency hides under the param phase) ----
  float4 st[6];
#pragma unroll
  for (int it = 0; it < 6; ++it) st[it] = ((const float4*)inb)[tid + it * 512];

  // ---- wave 0: draws + params + ballot masks, entirely barrier-free ----
  if (tid < 64) {
    float myu = 0.f;
    if (tid < 17) {
      KeyPair k = KT.k[tid];
      uint32_t i = (tid == 3) ? 2u * (uint32_t)b
                 : (tid == 4) ? 2u * (uint32_t)b + 1u
                 : (uint32_t)b;
      myu = bits_to_unit(jax_rbits32(k, i));
    }
    float u[17];
#pragma unroll
    for (int j = 0; j < 17; ++j) u[j] = __shfl(myu, j);

    const float DEG = 0.017453292519943295f;
    const float ang = map_u(u[0], -25.f, 25.f) * DEG;
    const float shr = map_u(u[1], -15.f, 15.f) * DEG;
    const float scl = map_u(u[2], 0.85f, 1.15f);
    const float t_x = map_u(u[3], -0.15f, 0.15f) * 64.f;
    const float t_y = map_u(u[4], -0.15f, 0.15f) * 64.f;
    const float cA = cosf(ang), sA = sinf(ang), tS = tanf(shr);
    float area = map_u(u[10], 0.02f, 0.1f);
    area = area * 64.f;   // mirror reference's (u * H) * W evaluation order
    area = area * 64.f;
    const float ratio = map_u(u[11], 0.3f, 3.0f);
    const float eh = fminf(fmaxf(sqrtf(area * ratio), 1.f), 64.f);
    const float ew = fminf(fmaxf(sqrtf(area / ratio), 1.f), 64.f);
    const float topv = u[12] * (64.f - eh);
    const float leftv = u[13] * (64.f - ew);
    const float dG = floorf(map_u(u[15], 8.f, 32.f));
    const float lG = floorf(dG * 0.6f);

    const float rf = (float)tid;   // H == W == 64: rows and cols share lanes
    const unsigned long long g  = __ballot(fmodf(rf, dG) < lG);
    const unsigned long long er = __ballot((rf >= topv) & (rf < (topv + eh)));
    const unsigned long long ec = __ballot((rf >= leftv) & (rf < (leftv + ew)));
    if (tid == 0) {
      sp.m00 = (cA - tS * (-sA)) / scl;
      sp.m01 = (sA - tS * cA) / scl;
      sp.m10 = (-sA) / scl;
      sp.m11 = cA / scl;
      sp.txp = t_x; sp.typ = t_y;
      sp.flip = u[5] < 0.6f;
      sp.bb = map_u(u[6], 0.7f, 1.3f);
      sp.cc = map_u(u[7], 0.7f, 1.3f);
      sp.ssat = map_u(u[8], 0.8f, 1.2f);
      sp.doblur = u[9] < 0.3f;
      sp.apply_e = u[14] < 0.3f;
      sp.apply_g = u[16] < 0.3f;
      mgrid = g; merow = er; mecol = ec;
    }
  } else if (tid < 328) {
    // ---- zero the 264 border cells per plane (disjoint from data cells) ----
    const int z = tid - 64;
    int a;
    if (z < 65)       a = z;              // row 0 (y=-1)
    else if (z < 200) a = 4160 + z;       // 4225..4359: rows 65,66 + tail
    else              a = (z - 199) * RS; // left pad col of rows 1..64
#pragma unroll
    for (int c = 0; c < 3; ++c) simg[c * PLS + a] = 0.f;
  }

  // ---- staged data -> bordered LDS (compiler inserts the vmcnt waits) ----
#pragma unroll
  for (int it = 0; it < 6; ++it) {
    const int f = it * 2048 + tid * 4;
    const int c = f >> 12;
    const int r = (f >> 6) & 63;
    const int cc = f & 63;
    float* d = &simg[c * PLS + (r + 1) * RS + cc + 1];
    d[0] = st[it].x; d[1] = st[it].y; d[2] = st[it].z; d[3] = st[it].w;
  }
  __syncthreads();   // staging + params + masks visible

  // snapshot params into registers
  const float m00 = sp.m00, m01 = sp.m01, m10 = sp.m10, m11 = sp.m11;
  const float txp = sp.txp, typ = sp.typ;
  const float bb = sp.bb, cc = sp.cc, ssat = sp.ssat;
  const int flip = sp.flip, doblur = sp.doblur;
  const int apply_e = sp.apply_e, apply_g = sp.apply_g;
  const unsigned long long mg = mgrid, mer = merow, mec = mecol;

  // ---- phase 1: affine warp + hflip, results held in registers ----
  // Mapping/weights computed once per pixel, shared by all 3 channels.
  // Taps are plain reads: border zeros reproduce the reference's validity
  // masking exactly (clamped sx,sy land on weight-0 / value-0 cells).
  float vv[3][8];
  float lsum = 0.f;
#pragma unroll
  for (int it = 0; it < 8; ++it) {
    const int p = tid + it * 512;
    const int h = p >> 6;
    const int w = p & 63;
    const int wsrc = flip ? (63 - w) : w;   // flip(warp(x))[w] == warp-out at 63-w
    const float gx = (float)wsrc - 31.5f;
    const float gy = (float)h - 31.5f;
    float sx = (m00 * gx + m01 * gy) - txp + 31.5f;
    float sy = (m10 * gx + m11 * gy) - typ + 31.5f;
    sx = fminf(fmaxf(sx, -1.f), 64.f);
    sy = fminf(fmaxf(sy, -1.f), 64.f);
    const float fx0 = floorf(sx), fy0 = floorf(sy);
    const float wx = sx - fx0, wy = sy - fy0;
    const float omx = 1.f - wx, omy = 1.f - wy;
    const float w00 = omx * omy, w01 = wx * omy, w10 = omx * wy, w11 = wx * wy;
    const int a = ((int)fy0 + 1) * RS + (int)fx0 + 1;
#pragma unroll
    for (int c = 0; c < 3; ++c) {
      const float* t = &simg[c * PLS + a];
      // adjacent pairs (t[0],t[1]) and (t[RS],t[RS+1]) merge into ds_read2_b32
      const float v = t[0] * w00 + t[1] * w01 + t[RS] * w10 + t[RS + 1] * w11;
      vv[c][it] = v;
      lsum += v;
    }
  }
  {
    float wsum = lsum;
    for (int off = 32; off > 0; off >>= 1) wsum += __shfl_down(wsum, off);
    if ((tid & 63) == 0) red[tid >> 6] = wsum;
  }
  __syncthreads();   // red[] visible; all tap reads of the planes complete

  // ---- color-jitter algebra (blur and pointwise-affine color commute):
  //   x3_c = A*x_c + G*grayx + m'     (A = s*cc*bb, G = (1-s)*cc*bb, m' = mean*(1-cc))
  //   blur(x3)_c = A*bx_c + G*(luma . bx) + m'*blur(1),  blur(1) = edge(h)*edge(w)
  const float mean = (bb * (red[0] + red[1] + red[2] + red[3] +
                            red[4] + red[5] + red[6] + red[7])) / 12288.f;
  const float Ac = ssat * cc * bb;
  const float Gc = (1.f - ssat) * cc * bb;
  const float mprime = mean * (1.f - cc);
  float* __restrict__ ob = out + (size_t)b * 12288;

  if (!doblur) {
    // ---- 70% path: straight from registers, zero further LDS traffic ----
#pragma unroll
    for (int it = 0; it < 8; ++it) {
      const int p = tid + it * 512;
      const int h = p >> 6, w = p & 63;
      const bool do_er = apply_e && ((mer >> h) & 1ull) && ((mec >> w) & 1ull);
      const bool do_gr = apply_g && ((mg >> h) & 1ull) && ((mg >> w) & 1ull);
      const float gray = 0.299f * vv[0][it] + 0.587f * vv[1][it] + 0.114f * vv[2][it];
#pragma unroll
      for (int c = 0; c < 3; ++c) {
        float v = Ac * vv[c][it] + Gc * gray + mprime;
        if (do_er) {
          const uint32_t idx = ((uint32_t)(b * 3 + c) << 12) | (uint32_t)p;
          v = bits_to_unit(jax_rbits32(kv, idx));   // uniform fill [0,1)
        }
        if (do_gr) v = 0.f;
        ob[c * 4096 + p] = fminf(fmaxf(v, 0.f), 1.f);   // lane-stride-1: coalesced
      }
    }
  } else {
    // ---- 30% path: write warped planes back (borders stay zero = blur pad) ----
#pragma unroll
    for (int it = 0; it < 8; ++it) {
      const int p = tid + it * 512;
      const int a = ((p >> 6) + 1) * RS + (p & 63) + 1;
#pragma unroll
      for (int c = 0; c < 3; ++c) simg[c * PLS + a] = vv[c][it];
    }
    __syncthreads();
#pragma unroll 1
    for (int it = 0; it < 2; ++it) {
      const int qq = tid + it * 512;        // quad id 0..1023
      const int h = qq >> 4;
      const int w0 = (qq & 15) * 4;
      float px[3][4];
#pragma unroll
      for (int c = 0; c < 3; ++c) {
        float win[3][6];
#pragma unroll
        for (int r = 0; r < 3; ++r) {
          // row (h-1+r), cols w0-1..w0+4; borders supply the zero padding.
          const float* row = &simg[c * PLS + (h + r) * RS + w0 + 1];
#pragma unroll
          for (int k = 0; k < 6; ++k) win[r][k] = row[k - 1];
        }
#pragma unroll
        for (int j = 0; j < 4; ++j) {
          const float h0 = 0.25f * win[0][j] + 0.5f * win[0][j + 1] + 0.25f * win[0][j + 2];
          const float h1 = 0.25f * win[1][j] + 0.5f * win[1][j + 1] + 0.25f * win[1][j + 2];
          const float h2 = 0.25f * win[2][j] + 0.5f * win[2][j + 1] + 0.25f * win[2][j + 2];
          px[c][j] = 0.25f * h0 + 0.5f * h1 + 0.25f * h2;
        }
      }
      const float rowe = (h == 0 || h == 63) ? 0.75f : 1.f;
      const bool erow_b = apply_e && ((mer >> h) & 1ull);
      const bool grow_b = apply_g && ((mg >> h) & 1ull);
      float o[3][4];
#pragma unroll
      for (int j = 0; j < 4; ++j) {
        const int w = w0 + j;
        const float gray = 0.299f * px[0][j] + 0.587f * px[1][j] + 0.114f * px[2][j];
        const float cole = (w == 0 || w == 63) ? 0.75f : 1.f;
        const float moff = mprime * (rowe * cole);
        const bool do_er = erow_b && ((mec >> w) & 1ull);
        const bool do_gr = grow_b && ((mg >> w) & 1ull);
#pragma unroll
        for (int c = 0; c < 3; ++c) {
          float v = Ac * px[c][j] + Gc * gray + moff;
          if (do_er) {
            const uint32_t idx = ((uint32_t)(b * 3 + c) << 12) | (uint32_t)(h << 6) | (uint32_t)w;
            v = bits_to_unit(jax_rbits32(kv, idx));   // uniform fill [0,1)
          }
          if (do_gr) v = 0.f;
          o[c][j] = fminf(fmaxf(v, 0.f), 1.f);
        }
      }
#pragma unroll
      for (int c = 0; c < 3; ++c) {
        float4 stv; stv.x = o[c][0]; stv.y = o[c][1]; stv.z = o[c][2]; stv.w = o[c][3];
        *(float4*)&ob[c * 4096 + h * 64 + w0] = stv;
      }
    }
  }
}

extern "C" void kernel_launch(void* const* d_in, const int* in_sizes, int n_in,
                              void* d_out, int out_size, void* d_ws, size_t ws_size,
                              hipStream_t stream) {
  (void)n_in; (void)out_size; (void)d_ws; (void)ws_size;
  const float* x = (const float*)d_in[0];
  float* out = (float*)d_out;
  const int B = in_sizes[0] / (3 * 64 * 64);
  if (B <= 0) return;

  // Host-side key derivation (pure arithmetic; graph-capture safe).
  KeyPair root; root.hi = 0u; root.lo = 42u;           // jax.random.key(42)
  KeyPair kg = jax_split_child(root, 0);
  KeyPair kf = jax_split_child(root, 1);
  KeyPair kc = jax_split_child(root, 2);
  KeyPair kb = jax_split_child(root, 3);
  KeyPair ke = jax_split_child(root, 4);
  KeyPair km = jax_split_child(root, 5);

  KTab KT;
  KT.k[0]  = jax_split_child(kg, 0);   // angle
  KT.k[1]  = jax_split_child(kg, 1);   // shear
  KT.k[2]  = jax_split_child(kg, 2);   // scale
  KT.k[3]  = jax_split_child(kg, 3);   // translate x (idx 2b)
  KT.k[4]  = KT.k[3];                  // translate y (idx 2b+1)
  KT.k[5]  = kf;                       // hflip
  KT.k[6]  = jax_split_child(kc, 0);   // brightness
  KT.k[7]  = jax_split_child(kc, 1);   // contrast
  KT.k[8]  = jax_split_child(kc, 2);   // saturation
  KT.k[9]  = kb;                       // blur
  KT.k[10] = jax_split_child(ke, 0);   // area
  KT.k[11] = jax_split_child(ke, 1);   // ratio
  KT.k[12] = jax_split_child(ke, 2);   // top
  KT.k[13] = jax_split_child(ke, 3);   // left
  KT.k[14] = jax_split_child(ke, 5);   // apply (erase)
  KT.k[15] = jax_split_child(km, 0);   // grid d
  KT.k[16] = jax_split_child(km, 1);   // apply (grid)
  KeyPair kv = jax_split_child(ke, 4); // erase fill values

  aug_kernel<<<dim3(B), dim3(512), 0, stream>>>(x, out, KT, kv, B);
}